// Round 2
// baseline (1368.591 us; speedup 1.0000x reference)
//
#include <hip/hip_runtime.h>
#include <math.h>

#define DD 8192     // sketch dimension d
#define CC 768      // channels
#define SS 145      // sequence length
#define BB 32       // batch
#define SN 64       // sensor dim

// ---- kB geometry ----
#define NS 4        // c-slices per b
#define CSL (CC/NS) // 192

// ---- kD geometry ----
#define TN 64       // e-cols per block
#define CK 32       // c-chunk
#define SP 160      // padded s
#define LTS 164     // padded Lt row stride (floats): 164%32=4 -> 4-way store conflict, 16B-aligned reads
#define NTD 320     // threads (5 waves): 20 s-rows x 16 e-cols

// ---------------------------------------------------------------------------
// kB: build per-(b,slice) partial Z vectors with LDS atomics; no global
// atomics (each block owns its output slice). blockIdx.y==BB builds Z11.
//   Zuu[b,d]=sum u1[c]u2[e][h=d],  Zcr[b,d]=sum (u1[c]s2[e]+s1[c]u2[e])[h=d],
//   Z11[d]  =sum s1[c]s2[e][h=d],  h=(h1[c]+h2[e])&(D-1),
//   u[b,c]=b_sen[c]+sum_n sensor[b,n]W_sen[c,n], u1=u*s1, u2=u*s2.
// ---------------------------------------------------------------------------
__global__ __launch_bounds__(256) void kB(
    const float* __restrict__ sensor, const float* __restrict__ Wsen,
    const float* __restrict__ bsen,
    const int* __restrict__ h1, const int* __restrict__ h2,
    const int* __restrict__ s1, const int* __restrict__ s2,
    float* __restrict__ Zup, float* __restrict__ Zcp, float* __restrict__ Z1p)
{
    __shared__ float Za[DD], Zb[DD];              // 64 KB
    __shared__ float sens[SN];
    __shared__ float u2s[CC], s2f[CC];
    __shared__ int   h2s[CC];
    __shared__ float u1sl[CSL], s1sl[CSL];
    __shared__ int   h1sl[CSL];

    const int sl  = blockIdx.x;
    const int b   = blockIdx.y;        // BB -> Z11 block
    const int tid = threadIdx.x;
    const bool z11 = (b == BB);

    for (int d = tid; d < DD; d += 256) { Za[d] = 0.f; Zb[d] = 0.f; }
    if (!z11 && tid < SN) sens[tid] = sensor[b*SN + tid];
    __syncthreads();

    const int c0 = sl * CSL;
    for (int c = tid; c < CC; c += 256) {
        float f2 = (float)s2[c];
        float u  = 0.f;
        if (!z11) {
            u = bsen[c];
            const float* w = Wsen + c*SN;
            #pragma unroll 8
            for (int n = 0; n < SN; ++n) u += sens[n] * w[n];
        }
        u2s[c] = u * f2; s2f[c] = f2; h2s[c] = h2[c];
        if (c >= c0 && c < c0 + CSL) {
            float f1 = (float)s1[c];
            u1sl[c-c0] = u * f1; s1sl[c-c0] = f1; h1sl[c-c0] = h1[c];
        }
    }
    __syncthreads();

    // each thread caches its 3 e-values in registers
    float ue[3], se[3]; int he[3];
    #pragma unroll
    for (int k = 0; k < 3; ++k) {
        int e = tid + k*256;
        ue[k] = u2s[e]; se[k] = s2f[e]; he[k] = h2s[e];
    }

    if (z11) {
        for (int cc = 0; cc < CSL; ++cc) {
            float s1c = s1sl[cc]; int h1c = h1sl[cc];
            #pragma unroll
            for (int k = 0; k < 3; ++k)
                atomicAdd(&Za[(h1c + he[k]) & (DD-1)], s1c * se[k]);
        }
    } else {
        for (int cc = 0; cc < CSL; ++cc) {
            float u1c = u1sl[cc], s1c = s1sl[cc]; int h1c = h1sl[cc];
            #pragma unroll
            for (int k = 0; k < 3; ++k) {
                int ix = (h1c + he[k]) & (DD-1);
                atomicAdd(&Za[ix], u1c * ue[k]);
                atomicAdd(&Zb[ix], u1c * se[k] + s1c * ue[k]);
            }
        }
    }
    __syncthreads();

    if (z11) {
        float* da = Z1p + (size_t)sl*DD;
        for (int d = tid; d < DD; d += 256) da[d] = Za[d];
    } else {
        float* da = Zup + ((size_t)b*NS + sl)*DD;
        float* db = Zcp + ((size_t)b*NS + sl)*DD;
        for (int d = tid; d < DD; d += 256) { da[d] = Za[d]; db[d] = Zb[d]; }
    }
}

// ---------------------------------------------------------------------------
// kD: fused gather + dense quadratic forms.
// Grid (e-tile, b, m). m selects matrix Z_m in {Zuu[b], Zcr[b], Z11} and the
// s-dependent factors: ip += fL[s]*a1[s,:]^T M a2[s,:]*fR[s] with
//   m=0: (w2,w2)  m=1: (w2,bb)  m=2: (bb,bb),  M[c,e]=Z_m[(h1c+h2e)&8191].
// Per c-chunk: stage Lt[c][s] = (E+tok)*s1*fL and gathered Mt[c][e]; dense
// 8x4 register-tile FMAs; epilogue dots with right vector read from global,
// shuffle-reduces over the 16 e-cols, atomicAdd into Q[b,s].
// ---------------------------------------------------------------------------
__global__ __launch_bounds__(NTD) void kD(
    const float* __restrict__ E, const float* __restrict__ tok,
    const int* __restrict__ h1, const int* __restrict__ h2,
    const int* __restrict__ s1, const int* __restrict__ s2,
    const float* __restrict__ Ws2, const float* __restrict__ bs2,
    const float* __restrict__ Zup, const float* __restrict__ Zcp,
    const float* __restrict__ Z1p, float* __restrict__ Q)
{
    __shared__ __align__(16) float Zm[DD];        // 32 KB
    __shared__ __align__(16) float Lt[CK][LTS];   // 21 KB
    __shared__ __align__(16) float Mt[CK][TN];    // 8 KB
    __shared__ int   h1s[CC];
    __shared__ int   h2t[TN];
    __shared__ float fLs[SP], fRs[SP];

    const int et  = blockIdx.x;
    const int b   = blockIdx.y;
    const int m   = blockIdx.z;
    const int tid = threadIdx.x;
    const int e0  = et * TN;

    // stage Z_m = sum of NS partials
    const float* P = (m == 0) ? Zup + (size_t)b*NS*DD
                   : (m == 1) ? Zcp + (size_t)b*NS*DD
                              : Z1p;
    for (int d = tid; d < DD; d += NTD)
        Zm[d] = P[d] + P[DD + d] + P[2*DD + d] + P[3*DD + d];
    for (int c = tid; c < CC; c += NTD) h1s[c] = h1[c];
    if (tid < TN) h2t[tid] = h2[e0 + tid];
    for (int s = tid; s < SP; s += NTD) {
        float w2 = (s < SS) ? Ws2[s] : 0.f;
        float bb = (s < SS) ? bs2[s] : 0.f;
        fLs[s] = (m == 2) ? bb : w2;
        fRs[s] = (m == 0) ? w2 : bb;
    }
    __syncthreads();

    const int tc = tid & 15;          // e-col
    const int tr = tid >> 4;          // s-row (0..19)
    const int sBase = tr * 8;
    const int eBase = tc * 4;

    // staging thread mappings
    const int cL  = tid & 31;         // Lt: c within chunk
    const int sL0 = tid >> 5;         // Lt: s start, step 10
    const int eG  = tid & 63;         // Mt: e
    const int cG0 = tid >> 6;         // Mt: c start, step 5
    const int h2v = h2t[eG];

    float acc[8][4];
    #pragma unroll
    for (int i = 0; i < 8; ++i)
        #pragma unroll
        for (int j = 0; j < 4; ++j) acc[i][j] = 0.f;

    for (int ck = 0; ck < CC/CK; ++ck) {
        const int c0 = ck * CK;
        // --- stage Lt (coalesced E reads: 32 consecutive c per 32 lanes) ---
        {
            const float s1c = (float)s1[c0 + cL];
            const float t1  = tok[CC + c0 + cL] * s1c;
            const float* ep = E + ((size_t)b*SS + sL0)*CC + c0 + cL;
            #pragma unroll 4
            for (int k = 0; k < 16; ++k) {
                int s = sL0 + 10*k;
                float x = 0.f;
                if (s < SS) x = (ep[(size_t)10*k*CC] * s1c + t1) * fLs[s];
                Lt[cL][s] = x;
            }
        }
        // --- stage Mt (gather from Zm) ---
        for (int c = cG0; c < CK; c += 5)
            Mt[c][eG] = Zm[(h1s[c0 + c] + h2v) & (DD-1)];
        __syncthreads();

        // --- dense 8x4 outer-product accumulation ---
        #pragma unroll 4
        for (int c = 0; c < CK; ++c) {
            float4 l0 = *(const float4*)&Lt[c][sBase];
            float4 l1 = *(const float4*)&Lt[c][sBase + 4];
            float4 mv = *(const float4*)&Mt[c][eBase];
            float lv[8] = {l0.x,l0.y,l0.z,l0.w,l1.x,l1.y,l1.z,l1.w};
            float mw[4] = {mv.x,mv.y,mv.z,mv.w};
            #pragma unroll
            for (int i = 0; i < 8; ++i)
                #pragma unroll
                for (int j = 0; j < 4; ++j)
                    acc[i][j] += lv[i] * mw[j];
        }
        __syncthreads();
    }

    // --- epilogue: qv[s] = fR[s] * sum_j acc[i][j]*a2[s,e_j], reduce over tc ---
    const float4 tv  = *(const float4*)&tok[CC + e0 + eBase];
    const int4   s2v = *(const int4*)&s2[e0 + eBase];
    const float s2f0 = (float)s2v.x, s2f1 = (float)s2v.y,
                s2f2 = (float)s2v.z, s2f3 = (float)s2v.w;
    const float t20 = tv.x*s2f0, t21 = tv.y*s2f1, t22 = tv.z*s2f2, t23 = tv.w*s2f3;

    #pragma unroll
    for (int i = 0; i < 8; ++i) {
        int s = sBase + i;
        float qv = 0.f;
        if (s < SS) {
            const float4 ev = *(const float4*)&E[((size_t)b*SS + s)*CC + e0 + eBase];
            float a0 = ev.x*s2f0 + t20;
            float a1 = ev.y*s2f1 + t21;
            float a2 = ev.z*s2f2 + t22;
            float a3 = ev.w*s2f3 + t23;
            qv = fRs[s] * (acc[i][0]*a0 + acc[i][1]*a1 + acc[i][2]*a2 + acc[i][3]*a3);
        }
        qv += __shfl_xor(qv, 1);
        qv += __shfl_xor(qv, 2);
        qv += __shfl_xor(qv, 4);
        qv += __shfl_xor(qv, 8);
        if (tc == 0 && s < SS) atomicAdd(&Q[b*SS + s], qv);
    }
}

// ---------------------------------------------------------------------------
// kE: bp = sign(Q)*sqrt(|Q|+1e-5); L2-normalize over s; project W_out.
// ---------------------------------------------------------------------------
__global__ __launch_bounds__(256) void kE(
    const float* __restrict__ Q, const float* __restrict__ Wout,
    const float* __restrict__ bout, float* __restrict__ out)
{
    __shared__ float red[8];
    const int b = blockIdx.x, tid = threadIdx.x;
    float v = 0.f, w = 0.f;
    if (tid < SS) {
        float ip = Q[b*SS + tid];
        float sg = (ip > 0.f) ? 1.f : ((ip < 0.f) ? -1.f : 0.f);
        v = sg * sqrtf(fabsf(ip) + 1e-5f);
        w = v * Wout[tid];
    }
    float sq = v * v;
    #pragma unroll
    for (int off = 32; off > 0; off >>= 1) {
        sq += __shfl_down(sq, off, 64);
        w  += __shfl_down(w,  off, 64);
    }
    if ((tid & 63) == 0) { red[tid >> 6] = sq; red[4 + (tid >> 6)] = w; }
    __syncthreads();
    if (tid == 0) {
        float ssq  = red[0] + red[1] + red[2] + red[3];
        float sw   = red[4] + red[5] + red[6] + red[7];
        float norm = fmaxf(sqrtf(ssq), 1e-12f);
        out[b] = sw / norm + bout[0];
    }
}

// ---------------------------------------------------------------------------
extern "C" void kernel_launch(void* const* d_in, const int* in_sizes, int n_in,
                              void* d_out, int out_size, void* d_ws, size_t ws_size,
                              hipStream_t stream) {
    const float* sensor = (const float*)d_in[0];
    const float* E      = (const float*)d_in[1];
    // d_in[2] image_masks: shape-only, unused
    const int*   h1     = (const int*)d_in[3];
    const int*   h2     = (const int*)d_in[4];
    const int*   s1     = (const int*)d_in[5];
    const int*   s2     = (const int*)d_in[6];
    // d_in[7] d (=8192): hard-coded
    const float* Wsen   = (const float*)d_in[8];
    const float* bsen   = (const float*)d_in[9];
    const float* Ws2    = (const float*)d_in[10];
    const float* bs2    = (const float*)d_in[11];
    const float* Wout   = (const float*)d_in[12];
    const float* bout   = (const float*)d_in[13];
    const float* tok    = (const float*)d_in[14];
    float* out = (float*)d_out;

    float* ws  = (float*)d_ws;
    float* Zup = ws;                               // BB*NS*DD
    float* Zcp = Zup + (size_t)BB*NS*DD;           // BB*NS*DD
    float* Z1p = Zcp + (size_t)BB*NS*DD;           // NS*DD
    float* Q   = Z1p + (size_t)NS*DD;              // BB*SS
    // total ws use ~= (2*32*4*8192 + 4*8192 + 32*145)*4 B ~= 8.6 MB

    hipMemsetAsync(Q, 0, (size_t)BB*SS*sizeof(float), stream);

    kB<<<dim3(NS, BB+1), dim3(256), 0, stream>>>(
        sensor, Wsen, bsen, h1, h2, s1, s2, Zup, Zcp, Z1p);

    kD<<<dim3(CC/TN, BB, 3), dim3(NTD), 0, stream>>>(
        E, tok, h1, h2, s1, s2, Ws2, bs2, Zup, Zcp, Z1p, Q);

    kE<<<dim3(BB), dim3(256), 0, stream>>>(Q, Wout, bout, out);
}

// Round 3
// 973.473 us; speedup vs baseline: 1.4059x; 1.4059x over previous
//
#include <hip/hip_runtime.h>
#include <math.h>

#define DD 8192     // sketch dimension d
#define CC 768      // channels
#define SS 145      // sequence length
#define BB 32       // batch
#define SN 64       // sensor dim

// ---- kB geometry ----
#define NS 4        // c-slices per b
#define CSL (CC/NS) // 192

// ---- kD geometry ----
#define TN 128      // e-cols per block
#define NET (CC/TN) // 6 e-tiles
#define CK 32       // c-chunk
#define SP 160      // padded s
#define LTS 164     // padded Lt row stride (floats), mult of 4 for b128 reads
#define NTD 320     // threads (5 waves): 20 s-rows x 16 e-cols
#define NWG (NET*BB*3)

// ---------------------------------------------------------------------------
// kB: per-(b,slice) partial Z vectors via LDS atomics (no global atomics).
//   Zuu[b,d]=sum u1[c]u2[e][h=d], Zcr[b,d]=sum (u1[c]s2[e]+s1[c]u2[e])[h=d],
//   Z11[d]  =sum s1[c]s2[e][h=d],  h=(h1[c]+h2[e])&(D-1),
//   u[b,c]=b_sen[c]+sum_n sensor[b,n]W_sen[c,n], u1=u*s1, u2=u*s2.
// ---------------------------------------------------------------------------
__global__ __launch_bounds__(256) void kB(
    const float* __restrict__ sensor, const float* __restrict__ Wsen,
    const float* __restrict__ bsen,
    const int* __restrict__ h1, const int* __restrict__ h2,
    const int* __restrict__ s1, const int* __restrict__ s2,
    float* __restrict__ Zup, float* __restrict__ Zcp, float* __restrict__ Z1p)
{
    __shared__ float Za[DD], Zb[DD];              // 64 KB
    __shared__ float sens[SN];
    __shared__ float u2s[CC], s2f[CC];
    __shared__ int   h2s[CC];
    __shared__ float u1sl[CSL], s1sl[CSL];
    __shared__ int   h1sl[CSL];

    const int sl  = blockIdx.x;
    const int b   = blockIdx.y;        // BB -> Z11 block
    const int tid = threadIdx.x;
    const bool z11 = (b == BB);

    for (int d = tid; d < DD; d += 256) { Za[d] = 0.f; Zb[d] = 0.f; }
    if (!z11 && tid < SN) sens[tid] = sensor[b*SN + tid];
    __syncthreads();

    const int c0 = sl * CSL;
    for (int c = tid; c < CC; c += 256) {
        float f2 = (float)s2[c];
        float u  = 0.f;
        if (!z11) {
            u = bsen[c];
            const float* w = Wsen + c*SN;
            #pragma unroll 8
            for (int n = 0; n < SN; ++n) u += sens[n] * w[n];
        }
        u2s[c] = u * f2; s2f[c] = f2; h2s[c] = h2[c];
        if (c >= c0 && c < c0 + CSL) {
            float f1 = (float)s1[c];
            u1sl[c-c0] = u * f1; s1sl[c-c0] = f1; h1sl[c-c0] = h1[c];
        }
    }
    __syncthreads();

    float ue[3], se[3]; int he[3];
    #pragma unroll
    for (int k = 0; k < 3; ++k) {
        int e = tid + k*256;
        ue[k] = u2s[e]; se[k] = s2f[e]; he[k] = h2s[e];
    }

    if (z11) {
        for (int cc = 0; cc < CSL; ++cc) {
            float s1c = s1sl[cc]; int h1c = h1sl[cc];
            #pragma unroll
            for (int k = 0; k < 3; ++k)
                atomicAdd(&Za[(h1c + he[k]) & (DD-1)], s1c * se[k]);
        }
    } else {
        for (int cc = 0; cc < CSL; ++cc) {
            float u1c = u1sl[cc], s1c = s1sl[cc]; int h1c = h1sl[cc];
            #pragma unroll
            for (int k = 0; k < 3; ++k) {
                int ix = (h1c + he[k]) & (DD-1);
                atomicAdd(&Za[ix], u1c * ue[k]);
                atomicAdd(&Zb[ix], u1c * se[k] + s1c * ue[k]);
            }
        }
    }
    __syncthreads();

    if (z11) {
        float* da = Z1p + (size_t)sl*DD;
        for (int d = tid; d < DD; d += 256) da[d] = Za[d];
    } else {
        float* da = Zup + ((size_t)b*NS + sl)*DD;
        float* db = Zcp + ((size_t)b*NS + sl)*DD;
        for (int d = tid; d < DD; d += 256) { da[d] = Za[d]; db[d] = Zb[d]; }
    }
}

// ---------------------------------------------------------------------------
// kC: sum the NS partials into the final Zs[65][DD]:
//   a in [0,32): Zuu_b ; a in [32,64): Zcr_b ; a==64: Z11.
// ---------------------------------------------------------------------------
__global__ __launch_bounds__(256) void kC(
    const float* __restrict__ Zup, const float* __restrict__ Zcp,
    const float* __restrict__ Z1p, float* __restrict__ Zs)
{
    const int a  = blockIdx.y;
    const int d4 = blockIdx.x*256 + threadIdx.x;     // float4 index, DD/4=2048
    const float4* P = (const float4*)(
        (a < BB)      ? Zup + (size_t)a*NS*DD :
        (a < 2*BB)    ? Zcp + (size_t)(a-BB)*NS*DD : Z1p);
    float4 v0 = P[d4], v1 = P[DD/4 + d4], v2 = P[2*DD/4 + d4], v3 = P[3*DD/4 + d4];
    float4 r;
    r.x = v0.x+v1.x+v2.x+v3.x; r.y = v0.y+v1.y+v2.y+v3.y;
    r.z = v0.z+v1.z+v2.z+v3.z; r.w = v0.w+v1.w+v2.w+v3.w;
    ((float4*)(Zs + (size_t)a*DD))[d4] = r;
}

// ---------------------------------------------------------------------------
// kD: fused gather + dense quadratic forms.
// 1D grid, XCD-swizzled -> (et, b, m). Per block: stage Zm (32 KB, L2-hot),
// then loop c-chunks: stage Lt[c][s]=x*s1*fL (x=E+tok1) and gathered
// Mt[c][e]=Zm[(h1c+h2e)&8191]; dense 8x8 register-tile FMAs; epilogue dots
// with a2*fR, shuffle-reduces over 16 e-lanes, atomicAdd into Q[b,s].
//   m=0:(w2,w2)*Zuu[b]  m=1:(w2,bb)*Zcr[b]  m=2:(bb,bb)*Z11.
// ---------------------------------------------------------------------------
__global__ __launch_bounds__(NTD) void kD(
    const float* __restrict__ E, const float* __restrict__ tok,
    const int* __restrict__ h1, const int* __restrict__ h2,
    const int* __restrict__ s1, const int* __restrict__ s2,
    const float* __restrict__ Ws2, const float* __restrict__ bs2,
    const float* __restrict__ Zs, float* __restrict__ Q)
{
    __shared__ __align__(16) float Zm[DD];        // 32 KB
    __shared__ __align__(16) float Lt[CK][LTS];   // 21 KB
    __shared__ __align__(16) float Mt[CK][TN];    // 16 KB
    __shared__ int   h1s[CC];                     // 3 KB
    __shared__ int   h2g[TN];
    __shared__ float fLs[SP], fRs[SP];

    // XCD swizzle: 576 blocks, 72 per XCD -> 4 consecutive b per XCD
    const int wg = (blockIdx.x & 7)*(NWG/8) + (blockIdx.x >> 3);
    const int b  = wg / (NET*3);
    const int r  = wg % (NET*3);
    const int m  = r / NET;
    const int et = r % NET;
    const int tid = threadIdx.x;
    const int e0  = et * TN;

    // stage Zm (coalesced float4 from L2-resident summed Zs)
    {
        const float4* Zsrc = (const float4*)(Zs +
            (size_t)((m == 0) ? b : (m == 1) ? (BB + b) : 2*BB) * DD);
        float4* Zm4 = (float4*)Zm;
        for (int i = tid; i < DD/4; i += NTD) Zm4[i] = Zsrc[i];
    }
    for (int c = tid; c < CC; c += NTD) h1s[c] = h1[c];
    if (tid < TN) h2g[tid] = h2[e0 + tid];
    if (tid < SP) {
        float w2 = (tid < SS) ? Ws2[tid] : 0.f;
        float bbv = (tid < SS) ? bs2[tid] : 0.f;
        fLs[tid] = (m == 2) ? bbv : w2;
        fRs[tid] = (m == 0) ? w2 : bbv;
    }
    __syncthreads();

    const int tc = tid & 15;          // e-col group
    const int tr = tid >> 4;          // s-row group (0..19)
    const int sBase = tr * 8;
    const int eA = tc * 4;            // low e half
    const int eB = 64 + tc * 4;       // high e half

    // staging thread mappings for Lt
    const int cL  = tid & 31;
    const int sL0 = tid >> 5;         // 0..9

    float acc[8][8];
    #pragma unroll
    for (int i = 0; i < 8; ++i)
        #pragma unroll
        for (int j = 0; j < 8; ++j) acc[i][j] = 0.f;

    for (int ck = 0; ck < CC/CK; ++ck) {
        const int c0 = ck * CK;
        // --- stage Lt (coalesced E reads) ---
        {
            const float s1c = (float)s1[c0 + cL];
            const float t1  = tok[CC + c0 + cL] * s1c;
            const float* ep = E + ((size_t)b*SS + sL0)*CC + c0 + cL;
            #pragma unroll 4
            for (int k = 0; k < 16; ++k) {
                int s = sL0 + 10*k;
                float x = 0.f;
                if (s < SS) x = (ep[(size_t)10*k*CC] * s1c + t1) * fLs[s];
                Lt[cL][s] = x;
            }
        }
        // --- stage Mt (gather from Zm) ---
        for (int i = tid; i < CK*TN; i += NTD) {
            int c = i >> 7, e = i & (TN-1);
            Mt[c][e] = Zm[(h1s[c0 + c] + h2g[e]) & (DD-1)];
        }
        __syncthreads();

        // --- dense 8x8 outer-product accumulation ---
        #pragma unroll 4
        for (int c = 0; c < CK; ++c) {
            float4 l0 = *(const float4*)&Lt[c][sBase];
            float4 l1 = *(const float4*)&Lt[c][sBase + 4];
            float4 m0 = *(const float4*)&Mt[c][eA];
            float4 m1 = *(const float4*)&Mt[c][eB];
            float lv[8] = {l0.x,l0.y,l0.z,l0.w,l1.x,l1.y,l1.z,l1.w};
            float mw[8] = {m0.x,m0.y,m0.z,m0.w,m1.x,m1.y,m1.z,m1.w};
            #pragma unroll
            for (int i = 0; i < 8; ++i)
                #pragma unroll
                for (int j = 0; j < 8; ++j)
                    acc[i][j] += lv[i] * mw[j];
        }
        __syncthreads();
    }

    // --- epilogue: qv[s] = fR[s] * sum_j acc[i][j]*a2[s,e_j], reduce over tc ---
    const float4 tvA  = *(const float4*)&tok[CC + e0 + eA];
    const float4 tvB  = *(const float4*)&tok[CC + e0 + eB];
    const int4   sA   = *(const int4*)&s2[e0 + eA];
    const int4   sB   = *(const int4*)&s2[e0 + eB];
    const float sf[8] = {(float)sA.x,(float)sA.y,(float)sA.z,(float)sA.w,
                         (float)sB.x,(float)sB.y,(float)sB.z,(float)sB.w};
    const float tf[8] = {tvA.x*sf[0],tvA.y*sf[1],tvA.z*sf[2],tvA.w*sf[3],
                         tvB.x*sf[4],tvB.y*sf[5],tvB.z*sf[6],tvB.w*sf[7]};

    #pragma unroll
    for (int i = 0; i < 8; ++i) {
        int s = sBase + i;
        float qv = 0.f;
        if (s < SS) {
            const float* erow = E + ((size_t)b*SS + s)*CC + e0;
            const float4 evA = *(const float4*)&erow[eA];
            const float4 evB = *(const float4*)&erow[eB];
            float av[8] = {evA.x*sf[0]+tf[0], evA.y*sf[1]+tf[1],
                           evA.z*sf[2]+tf[2], evA.w*sf[3]+tf[3],
                           evB.x*sf[4]+tf[4], evB.y*sf[5]+tf[5],
                           evB.z*sf[6]+tf[6], evB.w*sf[7]+tf[7]};
            float t = 0.f;
            #pragma unroll
            for (int j = 0; j < 8; ++j) t += acc[i][j] * av[j];
            qv = fRs[s] * t;
        }
        qv += __shfl_xor(qv, 1);
        qv += __shfl_xor(qv, 2);
        qv += __shfl_xor(qv, 4);
        qv += __shfl_xor(qv, 8);
        if (tc == 0 && s < SS) atomicAdd(&Q[b*SS + s], qv);
    }
}

// ---------------------------------------------------------------------------
// kE: bp = sign(Q)*sqrt(|Q|+1e-5); L2-normalize over s; project W_out.
// ---------------------------------------------------------------------------
__global__ __launch_bounds__(256) void kE(
    const float* __restrict__ Q, const float* __restrict__ Wout,
    const float* __restrict__ bout, float* __restrict__ out)
{
    __shared__ float red[8];
    const int b = blockIdx.x, tid = threadIdx.x;
    float v = 0.f, w = 0.f;
    if (tid < SS) {
        float ip = Q[b*SS + tid];
        float sg = (ip > 0.f) ? 1.f : ((ip < 0.f) ? -1.f : 0.f);
        v = sg * sqrtf(fabsf(ip) + 1e-5f);
        w = v * Wout[tid];
    }
    float sq = v * v;
    #pragma unroll
    for (int off = 32; off > 0; off >>= 1) {
        sq += __shfl_down(sq, off, 64);
        w  += __shfl_down(w,  off, 64);
    }
    if ((tid & 63) == 0) { red[tid >> 6] = sq; red[4 + (tid >> 6)] = w; }
    __syncthreads();
    if (tid == 0) {
        float ssq  = red[0] + red[1] + red[2] + red[3];
        float sw   = red[4] + red[5] + red[6] + red[7];
        float norm = fmaxf(sqrtf(ssq), 1e-12f);
        out[b] = sw / norm + bout[0];
    }
}

// ---------------------------------------------------------------------------
extern "C" void kernel_launch(void* const* d_in, const int* in_sizes, int n_in,
                              void* d_out, int out_size, void* d_ws, size_t ws_size,
                              hipStream_t stream) {
    const float* sensor = (const float*)d_in[0];
    const float* E      = (const float*)d_in[1];
    const int*   h1     = (const int*)d_in[3];
    const int*   h2     = (const int*)d_in[4];
    const int*   s1     = (const int*)d_in[5];
    const int*   s2     = (const int*)d_in[6];
    const float* Wsen   = (const float*)d_in[8];
    const float* bsen   = (const float*)d_in[9];
    const float* Ws2    = (const float*)d_in[10];
    const float* bs2    = (const float*)d_in[11];
    const float* Wout   = (const float*)d_in[12];
    const float* bout   = (const float*)d_in[13];
    const float* tok    = (const float*)d_in[14];
    float* out = (float*)d_out;

    float* ws  = (float*)d_ws;
    float* Zup = ws;                               // BB*NS*DD
    float* Zcp = Zup + (size_t)BB*NS*DD;           // BB*NS*DD
    float* Z1p = Zcp + (size_t)BB*NS*DD;           // NS*DD
    float* Zs  = Z1p + (size_t)NS*DD;              // 65*DD (summed)
    float* Q   = Zs  + (size_t)(2*BB+1)*DD;        // BB*SS
    // total ws use ~= (2*32*4 + 4 + 65)*8192*4 + 18.5K ~= 10.8 MB

    hipMemsetAsync(Q, 0, (size_t)BB*SS*sizeof(float), stream);

    kB<<<dim3(NS, BB+1), dim3(256), 0, stream>>>(
        sensor, Wsen, bsen, h1, h2, s1, s2, Zup, Zcp, Z1p);

    kC<<<dim3(DD/4/256, 2*BB+1), dim3(256), 0, stream>>>(Zup, Zcp, Z1p, Zs);

    kD<<<dim3(NWG), dim3(NTD), 0, stream>>>(
        E, tok, h1, h2, s1, s2, Ws2, bs2, Zs, Q);

    kE<<<dim3(BB), dim3(256), 0, stream>>>(Q, Wout, bout, out);
}

// Round 4
// 909.963 us; speedup vs baseline: 1.5040x; 1.0698x over previous
//
#include <hip/hip_runtime.h>
#include <math.h>

#define DD 8192     // sketch dimension d
#define CC 768      // channels
#define SS 145      // sequence length
#define BB 32       // batch
#define SN 64       // sensor dim

// ---- kB geometry ----
#define NS 4        // c-slices per b
#define CSL (CC/NS) // 192

// ---- kD geometry ----
#define TN 128      // e-cols per block
#define NET (CC/TN) // 6 e-tiles
#define CK 16       // c-chunk
#define SP 160      // padded s extent (20 groups of 8)
#define LTS 164     // Lt row stride: mult of 4 (b128-aligned), bank stride 4 -> 2-way store conflict
#define NTD 320     // threads (5 waves): 20 s-groups x 16 e-groups
#define NWG (NET*BB*3)

// ---------------------------------------------------------------------------
// kB: per-(b,slice) partial Z vectors via LDS atomics (no global atomics).
//   Zuu[b,d]=sum u1[c]u2[e][h=d], Zcr[b,d]=sum (u1[c]s2[e]+s1[c]u2[e])[h=d],
//   Z11[d]  =sum s1[c]s2[e][h=d],  h=(h1[c]+h2[e])&(D-1),
//   u[b,c]=b_sen[c]+sum_n sensor[b,n]W_sen[c,n], u1=u*s1, u2=u*s2.
// ---------------------------------------------------------------------------
__global__ __launch_bounds__(256) void kB(
    const float* __restrict__ sensor, const float* __restrict__ Wsen,
    const float* __restrict__ bsen,
    const int* __restrict__ h1, const int* __restrict__ h2,
    const int* __restrict__ s1, const int* __restrict__ s2,
    float* __restrict__ Zup, float* __restrict__ Zcp, float* __restrict__ Z1p)
{
    __shared__ float Za[DD], Zb[DD];              // 64 KB
    __shared__ float sens[SN];
    __shared__ float u2s[CC], s2f[CC];
    __shared__ int   h2s[CC];
    __shared__ float u1sl[CSL], s1sl[CSL];
    __shared__ int   h1sl[CSL];

    const int sl  = blockIdx.x;
    const int b   = blockIdx.y;        // BB -> Z11 block
    const int tid = threadIdx.x;
    const bool z11 = (b == BB);

    for (int d = tid; d < DD; d += 256) { Za[d] = 0.f; Zb[d] = 0.f; }
    if (!z11 && tid < SN) sens[tid] = sensor[b*SN + tid];
    __syncthreads();

    const int c0 = sl * CSL;
    for (int c = tid; c < CC; c += 256) {
        float f2 = (float)s2[c];
        float u  = 0.f;
        if (!z11) {
            u = bsen[c];
            const float* w = Wsen + c*SN;
            #pragma unroll 8
            for (int n = 0; n < SN; ++n) u += sens[n] * w[n];
        }
        u2s[c] = u * f2; s2f[c] = f2; h2s[c] = h2[c];
        if (c >= c0 && c < c0 + CSL) {
            float f1 = (float)s1[c];
            u1sl[c-c0] = u * f1; s1sl[c-c0] = f1; h1sl[c-c0] = h1[c];
        }
    }
    __syncthreads();

    float ue[3], se[3]; int he[3];
    #pragma unroll
    for (int k = 0; k < 3; ++k) {
        int e = tid + k*256;
        ue[k] = u2s[e]; se[k] = s2f[e]; he[k] = h2s[e];
    }

    if (z11) {
        for (int cc = 0; cc < CSL; ++cc) {
            float s1c = s1sl[cc]; int h1c = h1sl[cc];
            #pragma unroll
            for (int k = 0; k < 3; ++k)
                atomicAdd(&Za[(h1c + he[k]) & (DD-1)], s1c * se[k]);
        }
    } else {
        for (int cc = 0; cc < CSL; ++cc) {
            float u1c = u1sl[cc], s1c = s1sl[cc]; int h1c = h1sl[cc];
            #pragma unroll
            for (int k = 0; k < 3; ++k) {
                int ix = (h1c + he[k]) & (DD-1);
                atomicAdd(&Za[ix], u1c * ue[k]);
                atomicAdd(&Zb[ix], u1c * se[k] + s1c * ue[k]);
            }
        }
    }
    __syncthreads();

    if (z11) {
        float* da = Z1p + (size_t)sl*DD;
        for (int d = tid; d < DD; d += 256) da[d] = Za[d];
    } else {
        float* da = Zup + ((size_t)b*NS + sl)*DD;
        float* db = Zcp + ((size_t)b*NS + sl)*DD;
        for (int d = tid; d < DD; d += 256) { da[d] = Za[d]; db[d] = Zb[d]; }
    }
}

// ---------------------------------------------------------------------------
// kC: sum the NS partials into the final Zs[65][DD]:
//   a in [0,32): Zuu_b ; a in [32,64): Zcr_b ; a==64: Z11.
// ---------------------------------------------------------------------------
__global__ __launch_bounds__(256) void kC(
    const float* __restrict__ Zup, const float* __restrict__ Zcp,
    const float* __restrict__ Z1p, float* __restrict__ Zs)
{
    const int a  = blockIdx.y;
    const int d4 = blockIdx.x*256 + threadIdx.x;     // float4 index, DD/4=2048
    const float4* P = (const float4*)(
        (a < BB)      ? Zup + (size_t)a*NS*DD :
        (a < 2*BB)    ? Zcp + (size_t)(a-BB)*NS*DD : Z1p);
    float4 v0 = P[d4], v1 = P[DD/4 + d4], v2 = P[2*DD/4 + d4], v3 = P[3*DD/4 + d4];
    float4 r;
    r.x = v0.x+v1.x+v2.x+v3.x; r.y = v0.y+v1.y+v2.y+v3.y;
    r.z = v0.z+v1.z+v2.z+v3.z; r.w = v0.w+v1.w+v2.w+v3.w;
    ((float4*)(Zs + (size_t)a*DD))[d4] = r;
}

// ---------------------------------------------------------------------------
// kD: fused gather + dense quadratic forms.
// 1D grid, XCD-swizzled -> (et, b, m). LDS kept under 54272 B so 3 blocks/CU
// co-reside (15 waves). Per block: stage Zm (32 KB, L2-hot); per c-chunk
// (CK=16): stage Lt[c][s]=x*s1*fL (x=E+tok1) and gathered
// Mt[c][e]=Zm[(h1c+h2e)&8191]; dense 8x8 register-tile FMAs; epilogue dots
// with a2, scales by fR (read from L1), reduces over 16 e-lanes, atomicAdd
// into Q[b,s].  m=0:(w2,w2)*Zuu[b]  m=1:(w2,bb)*Zcr[b]  m=2:(bb,bb)*Z11.
// ---------------------------------------------------------------------------
__global__ __launch_bounds__(NTD) void kD(
    const float* __restrict__ E, const float* __restrict__ tok,
    const int* __restrict__ h1, const int* __restrict__ h2,
    const int* __restrict__ s1, const int* __restrict__ s2,
    const float* __restrict__ Ws2, const float* __restrict__ bs2,
    const float* __restrict__ Zs, float* __restrict__ Q)
{
    __shared__ __align__(16) float Zm[DD];          // 32768 B
    __shared__ __align__(16) float Lt[CK][LTS];     // 10496 B
    __shared__ __align__(16) float Mt[CK][TN];      //  8192 B
    __shared__ unsigned short h1u[CC];              //  1536 B
    __shared__ unsigned short h2u[TN];              //   256 B
    __shared__ float fLs[148];                      //   592 B
    // total 53840 B -> 54272 rounded -> 3 blocks/CU

    // XCD swizzle: 576 blocks, 72 per XCD -> 4 consecutive b per XCD
    const int wg = (blockIdx.x & 7)*(NWG/8) + (blockIdx.x >> 3);
    const int b  = wg / (NET*3);
    const int r  = wg % (NET*3);
    const int m  = r / NET;
    const int et = r % NET;
    const int tid = threadIdx.x;
    const int e0  = et * TN;

    // stage Zm (coalesced float4 from L2-resident summed Zs)
    {
        const float4* Zsrc = (const float4*)(Zs +
            (size_t)((m == 0) ? b : (m == 1) ? (BB + b) : 2*BB) * DD);
        float4* Zm4 = (float4*)Zm;
        for (int i = tid; i < DD/4; i += NTD) Zm4[i] = Zsrc[i];
    }
    for (int c = tid; c < CC; c += NTD) h1u[c] = (unsigned short)h1[c];
    if (tid < TN) h2u[tid] = (unsigned short)h2[e0 + tid];
    if (tid < 148) {
        float w2  = (tid < SS) ? Ws2[tid] : 0.f;
        float bbv = (tid < SS) ? bs2[tid] : 0.f;
        fLs[tid] = (m == 2) ? bbv : w2;
    }
    __syncthreads();

    const int tc = tid & 15;          // e-col group
    const int tr = tid >> 4;          // s-row group (0..19)
    const int sBase = tr * 8;
    const int eA = tc * 4;            // low e half
    const int eB = 64 + tc * 4;       // high e half

    // staging thread mappings for Lt: 16 c x 20 s-starts
    const int cL  = tid & 15;
    const int sL0 = tid >> 4;         // 0..19

    float acc[8][8];
    #pragma unroll
    for (int i = 0; i < 8; ++i)
        #pragma unroll
        for (int j = 0; j < 8; ++j) acc[i][j] = 0.f;

    for (int ck = 0; ck < CC/CK; ++ck) {
        const int c0 = ck * CK;
        // --- stage Lt (coalesced E reads: 16 consecutive c per 16 lanes) ---
        {
            const float s1c = (float)s1[c0 + cL];
            const float t1  = tok[CC + c0 + cL] * s1c;
            const float* ep = E + ((size_t)b*SS + sL0)*CC + c0 + cL;
            #pragma unroll
            for (int k = 0; k < 8; ++k) {
                int s = sL0 + 20*k;
                float x = 0.f;
                if (s < SS) x = (ep[(size_t)20*k*CC] * s1c + t1) * fLs[s];
                Lt[cL][s] = x;
            }
        }
        // --- stage Mt (gather from Zm) ---
        for (int i = tid; i < CK*TN; i += NTD) {
            int c = i >> 7, e = i & (TN-1);
            Mt[c][e] = Zm[((int)h1u[c0 + c] + (int)h2u[e]) & (DD-1)];
        }
        __syncthreads();

        // --- dense 8x8 outer-product accumulation ---
        #pragma unroll
        for (int c = 0; c < CK; ++c) {
            float4 l0 = *(const float4*)&Lt[c][sBase];
            float4 l1 = *(const float4*)&Lt[c][sBase + 4];
            float4 m0 = *(const float4*)&Mt[c][eA];
            float4 m1 = *(const float4*)&Mt[c][eB];
            float lv[8] = {l0.x,l0.y,l0.z,l0.w,l1.x,l1.y,l1.z,l1.w};
            float mw[8] = {m0.x,m0.y,m0.z,m0.w,m1.x,m1.y,m1.z,m1.w};
            #pragma unroll
            for (int i = 0; i < 8; ++i)
                #pragma unroll
                for (int j = 0; j < 8; ++j)
                    acc[i][j] += lv[i] * mw[j];
        }
        __syncthreads();
    }

    // --- epilogue: qv[s] = fR[s] * sum_j acc[i][j]*a2[s,e_j], reduce over tc ---
    const float4 tvA  = *(const float4*)&tok[CC + e0 + eA];
    const float4 tvB  = *(const float4*)&tok[CC + e0 + eB];
    const int4   sA   = *(const int4*)&s2[e0 + eA];
    const int4   sB   = *(const int4*)&s2[e0 + eB];
    const float sf[8] = {(float)sA.x,(float)sA.y,(float)sA.z,(float)sA.w,
                         (float)sB.x,(float)sB.y,(float)sB.z,(float)sB.w};
    const float tf[8] = {tvA.x*sf[0],tvA.y*sf[1],tvA.z*sf[2],tvA.w*sf[3],
                         tvB.x*sf[4],tvB.y*sf[5],tvB.z*sf[6],tvB.w*sf[7]};

    #pragma unroll
    for (int i = 0; i < 8; ++i) {
        int s = sBase + i;
        float qv = 0.f;
        if (s < SS) {
            const float* erow = E + ((size_t)b*SS + s)*CC + e0;
            const float4 evA = *(const float4*)&erow[eA];
            const float4 evB = *(const float4*)&erow[eB];
            float av[8] = {evA.x*sf[0]+tf[0], evA.y*sf[1]+tf[1],
                           evA.z*sf[2]+tf[2], evA.w*sf[3]+tf[3],
                           evB.x*sf[4]+tf[4], evB.y*sf[5]+tf[5],
                           evB.z*sf[6]+tf[6], evB.w*sf[7]+tf[7]};
            float t = 0.f;
            #pragma unroll
            for (int j = 0; j < 8; ++j) t += acc[i][j] * av[j];
            qv = t;
        }
        qv += __shfl_xor(qv, 1);
        qv += __shfl_xor(qv, 2);
        qv += __shfl_xor(qv, 4);
        qv += __shfl_xor(qv, 8);
        if (tc == 0 && s < SS) {
            float fR = (m == 0) ? Ws2[s] : bs2[s];
            atomicAdd(&Q[b*SS + s], fR * qv);
        }
    }
}

// ---------------------------------------------------------------------------
// kE: bp = sign(Q)*sqrt(|Q|+1e-5); L2-normalize over s; project W_out.
// ---------------------------------------------------------------------------
__global__ __launch_bounds__(256) void kE(
    const float* __restrict__ Q, const float* __restrict__ Wout,
    const float* __restrict__ bout, float* __restrict__ out)
{
    __shared__ float red[8];
    const int b = blockIdx.x, tid = threadIdx.x;
    float v = 0.f, w = 0.f;
    if (tid < SS) {
        float ip = Q[b*SS + tid];
        float sg = (ip > 0.f) ? 1.f : ((ip < 0.f) ? -1.f : 0.f);
        v = sg * sqrtf(fabsf(ip) + 1e-5f);
        w = v * Wout[tid];
    }
    float sq = v * v;
    #pragma unroll
    for (int off = 32; off > 0; off >>= 1) {
        sq += __shfl_down(sq, off, 64);
        w  += __shfl_down(w,  off, 64);
    }
    if ((tid & 63) == 0) { red[tid >> 6] = sq; red[4 + (tid >> 6)] = w; }
    __syncthreads();
    if (tid == 0) {
        float ssq  = red[0] + red[1] + red[2] + red[3];
        float sw   = red[4] + red[5] + red[6] + red[7];
        float norm = fmaxf(sqrtf(ssq), 1e-12f);
        out[b] = sw / norm + bout[0];
    }
}

// ---------------------------------------------------------------------------
extern "C" void kernel_launch(void* const* d_in, const int* in_sizes, int n_in,
                              void* d_out, int out_size, void* d_ws, size_t ws_size,
                              hipStream_t stream) {
    const float* sensor = (const float*)d_in[0];
    const float* E      = (const float*)d_in[1];
    const int*   h1     = (const int*)d_in[3];
    const int*   h2     = (const int*)d_in[4];
    const int*   s1     = (const int*)d_in[5];
    const int*   s2     = (const int*)d_in[6];
    const float* Wsen   = (const float*)d_in[8];
    const float* bsen   = (const float*)d_in[9];
    const float* Ws2    = (const float*)d_in[10];
    const float* bs2    = (const float*)d_in[11];
    const float* Wout   = (const float*)d_in[12];
    const float* bout   = (const float*)d_in[13];
    const float* tok    = (const float*)d_in[14];
    float* out = (float*)d_out;

    float* ws  = (float*)d_ws;
    float* Zup = ws;                               // BB*NS*DD
    float* Zcp = Zup + (size_t)BB*NS*DD;           // BB*NS*DD
    float* Z1p = Zcp + (size_t)BB*NS*DD;           // NS*DD
    float* Zs  = Z1p + (size_t)NS*DD;              // 65*DD (summed)
    float* Q   = Zs  + (size_t)(2*BB+1)*DD;        // BB*SS
    // total ws use ~= (2*32*4 + 4 + 65)*8192*4 + 18.5K ~= 10.8 MB

    hipMemsetAsync(Q, 0, (size_t)BB*SS*sizeof(float), stream);

    kB<<<dim3(NS, BB+1), dim3(256), 0, stream>>>(
        sensor, Wsen, bsen, h1, h2, s1, s2, Zup, Zcp, Z1p);

    kC<<<dim3(DD/4/256, 2*BB+1), dim3(256), 0, stream>>>(Zup, Zcp, Z1p, Zs);

    kD<<<dim3(NWG), dim3(NTD), 0, stream>>>(
        E, tok, h1, h2, s1, s2, Ws2, bs2, Zs, Q);

    kE<<<dim3(BB), dim3(256), 0, stream>>>(Q, Wout, bout, out);
}